// Round 3
// baseline (651.631 us; speedup 1.0000x reference)
//
#include <hip/hip_runtime.h>

// Volume renderer (NeRF-style) — wave-per-ray, LDS-staged rgb.
// N_SAMPLES = 128, one 64-lane wave per ray, lane owns samples (2i, 2i+1).
// transmittance via exp(-prefix_sum(sigma*delta)):
//   T_i = exp(-sum_{j<i} x_j),  w_i = T_i - T_{i+1}
// NUMERICS: lane 63's x1 holds the 1e10 sentinel delta — kept OUT of the wave
// scan (would destroy the prefix by cancellation); re-added only into c1 whose
// sole use is exp(-c1) -> 0.
// rgb (57% of bytes) is staged block-wide through LDS with coalesced float4
// loads (the direct per-lane access is 24-B-strided: 3x the L1 line-visits).
// LDS reads are 8-B at bank stride 6 -> 2-way aliasing = free.

#define FAR_DELTA 1e10f

__global__ __launch_bounds__(256) void volrender_kernel(
    const float* __restrict__ rgb,       // [N, 128, 3]
    const float* __restrict__ density,   // [N, 128, 1]
    const float* __restrict__ dist,      // [N, 128]
    float* __restrict__ out,             // [N, 3]
    int n_rays)
{
    __shared__ float4 sh[384];           // 4 rays x 96 float4 = 6144 B

    const int tid  = threadIdx.x;
    const int lane = tid & 63;
    const int wid  = tid >> 6;           // wave id in block = ray slot
    const int ray  = blockIdx.x * 4 + wid;
    const bool live = (ray < n_rays);

    // --- stage rgb for the block's 4 rays: fully coalesced float4 loads ---
    {
        const float4* rgb4 = (const float4*)rgb;
        const size_t blk  = (size_t)blockIdx.x * 384;      // block base, float4 units
        const size_t tot4 = (size_t)n_rays * 96;           // total float4 in rgb
        if (blk + tid < tot4)       sh[tid]       = rgb4[blk + tid];
        if (tid < 128 && blk + tid + 256 < tot4)
                                    sh[tid + 256] = rgb4[blk + tid + 256];
    }

    // dist/density loads issue before the barrier — in flight during staging
    float2 dd = make_float2(0.f, 0.f);
    float2 ss = make_float2(0.f, 0.f);
    if (live) {
        const size_t base128 = (size_t)ray * 128;
        dd = ((const float2*)(dist    + base128))[lane];
        ss = ((const float2*)(density + base128))[lane];
    }
    __syncthreads();

    if (!live) return;   // no barriers after this point

    // delta for sample 2i  : d[2i+1] - d[2i]   (in-lane)
    // delta for sample 2i+1: d[2i+2] - d[2i+1] (next lane's dd.x); lane 63 -> 1e10
    float dnext  = __shfl_down(dd.x, 1);
    float delta0 = dd.y - dd.x;
    float delta1 = (lane == 63) ? FAR_DELTA : (dnext - dd.y);

    float x0 = ss.x * delta0;
    float x1 = ss.y * delta1;

    // exclude the sentinel term from the scan (cancellation hazard)
    float x1s = (lane == 63) ? 0.0f : x1;
    float s   = x0 + x1s;

    // inclusive wave scan of per-lane pair-sum
    float scan = s;
    #pragma unroll
    for (int off = 1; off < 64; off <<= 1) {
        float t = __shfl_up(scan, off);
        if (lane >= off) scan += t;
    }
    float cbase = scan - s;     // prefix over samples < 2i
    float c0 = cbase + x0;      // through sample 2i
    float c1 = c0 + x1;         // through sample 2i+1 (sentinel: huge on lane 63)

    float T0 = __expf(-cbase);
    float T1 = __expf(-c0);
    float T2 = __expf(-c1);     // lane 63: exp(-1e10*sigma) = 0
    float w0 = T0 - T1;
    float w1 = T1 - T2;

    // lane's 6 rgb floats from LDS: 3x ds_read_b64, bank stride 6 (2-way, free)
    const float* shf = (const float*)sh + wid * 384 + 6 * lane;
    float2 r0 = *(const float2*)(shf + 0);   // rgb[2i].r,   rgb[2i].g
    float2 r1 = *(const float2*)(shf + 2);   // rgb[2i].b,   rgb[2i+1].r
    float2 r2 = *(const float2*)(shf + 4);   // rgb[2i+1].g, rgb[2i+1].b

    float accR = w0 * r0.x + w1 * r1.y;
    float accG = w0 * r0.y + w1 * r2.x;
    float accB = w0 * r1.x + w1 * r2.y;

    // wave-wide reduction to lane 0
    #pragma unroll
    for (int off = 32; off; off >>= 1) {
        accR += __shfl_down(accR, off);
        accG += __shfl_down(accG, off);
        accB += __shfl_down(accB, off);
    }

    if (lane == 0) {
        float* o = out + (size_t)ray * 3;
        o[0] = accR;
        o[1] = accG;
        o[2] = accB;
    }
}

extern "C" void kernel_launch(void* const* d_in, const int* in_sizes, int n_in,
                              void* d_out, int out_size, void* d_ws, size_t ws_size,
                              hipStream_t stream) {
    const float* rgb     = (const float*)d_in[0];
    const float* density = (const float*)d_in[1];
    const float* dist    = (const float*)d_in[2];
    float* out = (float*)d_out;

    const int n_rays = in_sizes[2] / 128;   // distances is [N, 128]

    // one wave (64 lanes) per ray; 4 rays per 256-thread block
    const int block = 256;
    const int grid = (n_rays + 3) / 4;

    volrender_kernel<<<grid, block, 0, stream>>>(rgb, density, dist, out, n_rays);
}